// Round 2
// baseline (258.229 us; speedup 1.0000x reference)
//
#include <hip/hip_runtime.h>

// ParallelAttention router: q,k,v = x@Wq|Wk|Wv (16384x2048 @ 2048x64),
// out[t][i] = sum_j softmax_j(q_i*k_j) * v_j, fp32 in/out.
//
// Strategy: split-bf16 (hi/lo) MFMA GEMM fused with per-token softmax epilogue.
//   pack_w_kernel: lay out Wq|Wk|Wv as MFMA B-fragments (bf16 hi+lo) in d_ws.
//   router_kernel: 512 blocks x 256 thr; block = 32 tokens; wave = 32 rows x 48 cols
//                  (6 16x16x32 tiles, 3 MFMAs each for hi*hi+lo*hi+hi*lo).
//   No barriers in K-loop; A direct global->reg, B fragments from L2.

typedef __bf16 bf16x8 __attribute__((ext_vector_type(8)));
typedef float f32x4  __attribute__((ext_vector_type(4)));

#define NTOK   16384
#define HDIM   2048
#define NCHUNK 64              // K chunks of 32
#define CH_STRIDE (12 * 2 * 512)  // bf16 elems per chunk in bfrag

// bfrag layout: [chunk 0..63][tile 0..11][hi=0/lo=1][lane 0..63][j 0..7]
// element = W_cat[k = chunk*32 + (lane>>4)*8 + j][n = tile*16 + (lane&15)]
// where W_cat cols: 0-63 = Wq, 64-127 = Wk, 128-191 = Wv.
__global__ void pack_w_kernel(const float* __restrict__ Wq,
                              const float* __restrict__ Wk,
                              const float* __restrict__ Wv,
                              __bf16* __restrict__ bfrag)
{
  int u = blockIdx.x * blockDim.x + threadIdx.x;   // (chunk, tile, lane)
  if (u >= NCHUNK * 12 * 64) return;
  int l  = u & 63;
  int tn = (u >> 6) % 12;
  int c  = u / (12 * 64);
  int n  = tn * 16 + (l & 15);
  int kb = c * 32 + ((l >> 4) << 3);
  const float* W = (n < 64) ? Wq : (n < 128) ? Wk : Wv;
  int nn = n & 63;
  bf16x8 hi, lo;
#pragma unroll
  for (int j = 0; j < 8; ++j) {
    float f = W[(size_t)(kb + j) * 64 + nn];
    __bf16 h = (__bf16)f;              // RNE
    hi[j] = h;
    lo[j] = (__bf16)(f - (float)h);    // residual
  }
  size_t base = (size_t)(c * 12 + tn) * 1024 + (size_t)l * 8;
  *(bf16x8*)(bfrag + base)       = hi;
  *(bf16x8*)(bfrag + base + 512) = lo;
}

__global__ __launch_bounds__(256, 2) void router_kernel(
    const float* __restrict__ x,
    const __bf16* __restrict__ bfrag,
    float* __restrict__ out)
{
  const int tok0 = blockIdx.x * 32;
  const int w    = threadIdx.x >> 6;   // col group: cols [48w, 48w+48)
  const int lane = threadIdx.x & 63;
  const int mr   = lane & 15;
  const int quad = lane >> 4;

  __shared__ float qkv[32 * 196];      // 32 tokens x 192 (+4 pad), fp32

  // A: row-tile i covers tokens tok0+16i .. +15; lane reads 8 consecutive k.
  const float*  a0 = x + (size_t)(tok0 + mr) * HDIM + quad * 8;
  const float*  a1 = a0 + 16 * HDIM;
  const __bf16* bp = bfrag + (size_t)(3 * w) * 1024 + (size_t)lane * 8;

  f32x4 acc[2][3];
#pragma unroll
  for (int i = 0; i < 2; ++i)
#pragma unroll
    for (int t = 0; t < 3; ++t)
      acc[i][t] = (f32x4){0.f, 0.f, 0.f, 0.f};

  // register prefetch (1 chunk deep)
  float4 pA[4];
  bf16x8 pBh[3], pBl[3];
  pA[0] = *(const float4*)(a0);
  pA[1] = *(const float4*)(a0 + 4);
  pA[2] = *(const float4*)(a1);
  pA[3] = *(const float4*)(a1 + 4);
#pragma unroll
  for (int t = 0; t < 3; ++t) {
    pBh[t] = *(const bf16x8*)(bp + (size_t)t * 1024);
    pBl[t] = *(const bf16x8*)(bp + (size_t)t * 1024 + 512);
  }

  for (int c = 0; c < NCHUNK; ++c) {
    float4 A[4]; bf16x8 Bh[3], Bl[3];
#pragma unroll
    for (int i = 0; i < 4; ++i) A[i] = pA[i];
#pragma unroll
    for (int t = 0; t < 3; ++t) { Bh[t] = pBh[t]; Bl[t] = pBl[t]; }

    if (c + 1 < NCHUNK) {
      const float*  na0 = a0 + (c + 1) * 32;
      const float*  na1 = a1 + (c + 1) * 32;
      const __bf16* nbp = bp + (size_t)(c + 1) * CH_STRIDE;
      pA[0] = *(const float4*)(na0);
      pA[1] = *(const float4*)(na0 + 4);
      pA[2] = *(const float4*)(na1);
      pA[3] = *(const float4*)(na1 + 4);
#pragma unroll
      for (int t = 0; t < 3; ++t) {
        pBh[t] = *(const bf16x8*)(nbp + (size_t)t * 1024);
        pBl[t] = *(const bf16x8*)(nbp + (size_t)t * 1024 + 512);
      }
    }

    // fp32 -> bf16 hi/lo split
    bf16x8 ah[2], al[2];
#pragma unroll
    for (int i = 0; i < 2; ++i) {
      float av[8] = {A[2*i].x, A[2*i].y, A[2*i].z, A[2*i].w,
                     A[2*i+1].x, A[2*i+1].y, A[2*i+1].z, A[2*i+1].w};
#pragma unroll
      for (int j = 0; j < 8; ++j) {
        __bf16 h = (__bf16)av[j];
        ah[i][j] = h;
        al[i][j] = (__bf16)(av[j] - (float)h);
      }
    }

#pragma unroll
    for (int i = 0; i < 2; ++i)
#pragma unroll
      for (int t = 0; t < 3; ++t) {
        acc[i][t] = __builtin_amdgcn_mfma_f32_16x16x32_bf16(ah[i], Bh[t], acc[i][t], 0, 0, 0);
        acc[i][t] = __builtin_amdgcn_mfma_f32_16x16x32_bf16(al[i], Bh[t], acc[i][t], 0, 0, 0);
        acc[i][t] = __builtin_amdgcn_mfma_f32_16x16x32_bf16(ah[i], Bl[t], acc[i][t], 0, 0, 0);
      }
  }

  // C/D layout (m89-verified): col = lane&15, row = (lane>>4)*4 + reg
#pragma unroll
  for (int i = 0; i < 2; ++i)
#pragma unroll
    for (int t = 0; t < 3; ++t) {
      int col = w * 48 + t * 16 + mr;
      int row = i * 16 + quad * 4;
#pragma unroll
      for (int r = 0; r < 4; ++r)
        qkv[(row + r) * 196 + col] = acc[i][t][r];
    }
  __syncthreads();

  // softmax epilogue: 8 threads per token, 8 outputs each.
  // No max-subtraction needed: |q_i*k_j| <~ 26, exp2(26*1.44) well inside fp32.
  const int tt = threadIdx.x >> 3;
  const int g  = threadIdx.x & 7;
  const float* qrow = qkv + tt * 196;
  float qs[8], lsum[8], osum[8];
#pragma unroll
  for (int ii = 0; ii < 8; ++ii) {
    qs[ii]   = qrow[g * 8 + ii] * 1.44269504f;   // log2(e)
    lsum[ii] = 0.f;
    osum[ii] = 0.f;
  }
  for (int j = 0; j < 64; ++j) {
    float kj = qrow[64 + j];
    float vj = qrow[128 + j];
#pragma unroll
    for (int ii = 0; ii < 8; ++ii) {
      float e = __builtin_amdgcn_exp2f(qs[ii] * kj);   // v_exp_f32
      lsum[ii] += e;
      osum[ii] = fmaf(e, vj, osum[ii]);
    }
  }
  float4 r0, r1;
  r0.x = osum[0] / lsum[0]; r0.y = osum[1] / lsum[1];
  r0.z = osum[2] / lsum[2]; r0.w = osum[3] / lsum[3];
  r1.x = osum[4] / lsum[4]; r1.y = osum[5] / lsum[5];
  r1.z = osum[6] / lsum[6]; r1.w = osum[7] / lsum[7];
  float* op = out + (size_t)(tok0 + tt) * 64 + g * 8;
  *(float4*)op       = r0;
  *(float4*)(op + 4) = r1;
}

extern "C" void kernel_launch(void* const* d_in, const int* in_sizes, int n_in,
                              void* d_out, int out_size, void* d_ws, size_t ws_size,
                              hipStream_t stream)
{
  const float* x  = (const float*)d_in[0];
  const float* Wq = (const float*)d_in[1];
  const float* Wk = (const float*)d_in[2];
  const float* Wv = (const float*)d_in[3];
  __bf16* bfrag   = (__bf16*)d_ws;          // needs 1.5 MiB of scratch
  float*  out     = (float*)d_out;

  pack_w_kernel<<<(NCHUNK * 12 * 64 + 255) / 256, 256, 0, stream>>>(Wq, Wk, Wv, bfrag);
  router_kernel<<<NTOK / 32, 256, 0, stream>>>(x, bfrag, out);
}